// Round 14
// baseline (127.479 us; speedup 1.0000x reference)
//
#include <hip/hip_runtime.h>

#define B_  2
#define L_  2048
#define D_  1024
#define H_  16
#define HD_ 64

typedef __attribute__((ext_vector_type(8))) short bf16x8;
typedef __attribute__((ext_vector_type(4))) float f32x4;

#define MFMA16(a, b, c) __builtin_amdgcn_mfma_f32_16x16x32_bf16(a, b, c, 0, 0, 0)

__device__ __forceinline__ unsigned short f2bf(float f) {
    union { float f; unsigned u; } v; v.f = f;
    unsigned r = v.u + 0x7FFFu + ((v.u >> 16) & 1u);
    return (unsigned short)(r >> 16);
}

// ---------------------------------------------------------------------------
// Merged prep: z<4 -> weight transposes (fp32 [K][N] -> bf16 [N][K]);
// z==4 -> x fp32 -> bf16 (grid-stride over the 32x32 block slab).
// ---------------------------------------------------------------------------
__global__ __launch_bounds__(256) void prep_all(
    const float* __restrict__ x,
    const float* __restrict__ Wq, const float* __restrict__ Wkv,
    const float* __restrict__ Wo,
    unsigned short* __restrict__ xb,
    unsigned short* __restrict__ Wqt, unsigned short* __restrict__ Wkvt,
    unsigned short* __restrict__ Wot)
{
    const int z = blockIdx.z;
    if (z == 4) {
        const int bidl = blockIdx.y * 32 + blockIdx.x;   // 0..1023
        const int n4 = B_ * L_ * D_ / 4;
        for (int i = bidl * 256 + threadIdx.x; i < n4; i += 1024 * 256) {
            float4 v = *(const float4*)(x + (size_t)i * 4);
            ushort4 u;
            u.x = f2bf(v.x); u.y = f2bf(v.y); u.z = f2bf(v.z); u.w = f2bf(v.w);
            *(ushort4*)(xb + (size_t)i * 4) = u;
        }
        return;
    }
    __shared__ float t[32][33];
    const float* W;  unsigned short* Wt;  int N, nc;
    if (z == 0)      { W = Wq;  Wt = Wqt;  N = 1024; nc = 0; }
    else if (z == 1) { W = Wo;  Wt = Wot;  N = 1024; nc = 0; }
    else             { W = Wkv; Wt = Wkvt; N = 2048; nc = (z - 2) * 1024; }
    const int tx = threadIdx.x & 31, ty = threadIdx.x >> 5;
    const int n0 = nc + blockIdx.x * 32, k0 = blockIdx.y * 32;
    #pragma unroll
    for (int r = 0; r < 4; ++r)
        t[ty + r * 8][tx] = W[(size_t)(k0 + ty + r * 8) * N + n0 + tx];
    __syncthreads();
    #pragma unroll
    for (int r = 0; r < 4; ++r)
        Wt[(size_t)(n0 + ty + r * 8) * 1024 + k0 + tx] = f2bf(t[tx][ty + r * 8]);
}

// ---------------------------------------------------------------------------
// Fused QKV projection v2: 256x128 tile (384 blocks -> 1.5/CU, makespan 0.75x
// of the 192-block 256^2 version), 8-phase pipelined schedule (T2+T3+T4+T5).
// LDS 96KB: A = 2dbuf x 2half x [128 rows][64], B = 2dbuf x 2half x [64][64].
// Per wave (8 = 2wm x 4wn): M = 2mh x (wm*64 + mi*16), N = 2nh x (wn*16).
// Stages/iter = A-h1(kt+1)[2] + B-h0(kt+1)[1] + A-h0(kt+2)[2] + B-h1(kt+2)[1]
// = 6 loads; loop-top vmcnt(3) keeps phases C+D stages (3 loads) in flight.
// Q (scaled) -> Qb, K -> dense Kb, V -> Vtg transposed.
// ---------------------------------------------------------------------------
__global__ __launch_bounds__(512, 1) void gemm_qkv8(
    const unsigned short* __restrict__ A,    // xb [4096][1024]
    const unsigned short* __restrict__ Bt,   // Wqkvt [3072][1024]
    const float* __restrict__ bq, const float* __restrict__ bkv,
    unsigned short* __restrict__ Qb, unsigned short* __restrict__ Kb,
    unsigned short* __restrict__ Vtg, float qscl)
{
    const int KDIM = 1024, NT = 16;  // K-tiles of 64
    __shared__ __align__(16) unsigned short lds[49152];  // 96 KiB

    const int tid = threadIdx.x;
    const int w = tid >> 6, l = tid & 63, g = l >> 4, ln = l & 15;
    const int wm = (w >> 2) & 1, wn = w & 3;

    // T1 XCD remap: 384 blocks -> 48 contiguous per XCD (384%8==0)
    const int lin = blockIdx.x;
    const int wg = (lin & 7) * 48 + (lin >> 3);
    const int by = wg / 24, bx = wg % 24;
    const int m0 = by * 256, n0 = bx * 128;

    const int sr8 = w * 8 + (l >> 3);            // 0..63
    const int sc  = (l & 7) ^ ((l >> 3) & 7);    // pre-swizzled source chunk
    const unsigned short* Asrc = A  + (size_t)m0 * KDIM + sc * 8;
    const unsigned short* Bsrc = Bt + (size_t)n0 * KDIM + sc * 8;

#define SLOT_A(d, h) (lds + ((d) * 2 + (h)) * 8192)            // 16KB slots
#define SLOT_B(d, h) (lds + 32768 + ((d) * 2 + (h)) * 4096)    // 8KB slots

    // A half-tile: 128 rows x 64 cols -> 2 loads/thread
#define STGA(slotp, hh, kt_) do {                                             \
    _Pragma("unroll")                                                         \
    for (int r_ = 0; r_ < 2; ++r_) {                                          \
        const int row_ = (hh) * 128 + r_ * 64 + sr8;                          \
        __builtin_amdgcn_global_load_lds(                                     \
            (const __attribute__((address_space(1))) void*)                   \
                (Asrc + (size_t)row_ * KDIM + (kt_) * 64),                    \
            (__attribute__((address_space(3))) void*)                         \
                ((slotp) + r_ * 4096 + w * 512 + l * 8),                      \
            16, 0, 0);                                                        \
    }                                                                         \
} while (0)

    // B half-tile: 64 rows x 64 cols -> 1 load/thread
#define STGB(slotp, hh, kt_) do {                                             \
    const int row_ = (hh) * 64 + sr8;                                         \
    __builtin_amdgcn_global_load_lds(                                         \
        (const __attribute__((address_space(1))) void*)                       \
            (Bsrc + (size_t)row_ * KDIM + (kt_) * 64),                        \
        (__attribute__((address_space(3))) void*)                             \
            ((slotp) + w * 512 + l * 8),                                      \
        16, 0, 0);                                                            \
} while (0)

    f32x4 acc[8][2];
    #pragma unroll
    for (int i = 0; i < 8; ++i)
        #pragma unroll
        for (int j = 0; j < 2; ++j) acc[i][j] = (f32x4){0.f, 0.f, 0.f, 0.f};

    bf16x8 aR[4][2], bB0[2], bB1[2];

    // prologue (age order); last two stage-ops = 3 loads stay in flight
    STGA(SLOT_A(0, 0), 0, 0);
    STGB(SLOT_B(0, 1), 1, 0);
    STGA(SLOT_A(0, 1), 1, 0);
    STGB(SLOT_B(0, 0), 0, 0);
    STGA(SLOT_A(1, 0), 0, 1);
    STGB(SLOT_B(1, 1), 1, 1);

    #pragma unroll 1
    for (int kt = 0; kt < NT; ++kt) {
        const int cur = kt & 1, nxt = cur ^ 1;
        asm volatile("s_waitcnt vmcnt(3)" ::: "memory");
        __builtin_amdgcn_s_barrier();

        // ---- phase A: (mh0, nh0) ----
        #pragma unroll
        for (int mi = 0; mi < 4; ++mi)
            #pragma unroll
            for (int kc = 0; kc < 2; ++kc) {
                const int rho = wm * 64 + mi * 16 + ln, c = kc * 4 + g;
                aR[mi][kc] = *(const bf16x8*)
                    (SLOT_A(cur, 0) + rho * 64 + ((c ^ (rho & 7)) * 8));
            }
        #pragma unroll
        for (int kc = 0; kc < 2; ++kc) {
            const int rho = wn * 16 + ln, c = kc * 4 + g;
            bB0[kc] = *(const bf16x8*)
                (SLOT_B(cur, 0) + rho * 64 + ((c ^ (rho & 7)) * 8));
        }
        if (kt + 1 < NT) STGA(SLOT_A(nxt, 1), 1, kt + 1);
        __builtin_amdgcn_s_barrier();
        asm volatile("s_waitcnt lgkmcnt(0)" ::: "memory");
        __builtin_amdgcn_s_setprio(1);
        #pragma unroll
        for (int mi = 0; mi < 4; ++mi) {
            acc[mi][0] = MFMA16(aR[mi][0], bB0[0], acc[mi][0]);
            acc[mi][0] = MFMA16(aR[mi][1], bB0[1], acc[mi][0]);
        }
        __builtin_amdgcn_s_setprio(0);
        __builtin_amdgcn_s_barrier();

        // ---- phase B: (mh0, nh1) ----
        #pragma unroll
        for (int kc = 0; kc < 2; ++kc) {
            const int rho = wn * 16 + ln, c = kc * 4 + g;
            bB1[kc] = *(const bf16x8*)
                (SLOT_B(cur, 1) + rho * 64 + ((c ^ (rho & 7)) * 8));
        }
        if (kt + 1 < NT) STGB(SLOT_B(nxt, 0), 0, kt + 1);
        __builtin_amdgcn_s_barrier();
        asm volatile("s_waitcnt lgkmcnt(0)" ::: "memory");
        __builtin_amdgcn_s_setprio(1);
        #pragma unroll
        for (int mi = 0; mi < 4; ++mi) {
            acc[mi][1] = MFMA16(aR[mi][0], bB1[0], acc[mi][1]);
            acc[mi][1] = MFMA16(aR[mi][1], bB1[1], acc[mi][1]);
        }
        __builtin_amdgcn_s_setprio(0);
        __builtin_amdgcn_s_barrier();

        // ---- phase C: (mh1, nh1) ----
        #pragma unroll
        for (int mi = 0; mi < 4; ++mi)
            #pragma unroll
            for (int kc = 0; kc < 2; ++kc) {
                const int rho = wm * 64 + mi * 16 + ln, c = kc * 4 + g;
                aR[mi][kc] = *(const bf16x8*)
                    (SLOT_A(cur, 1) + rho * 64 + ((c ^ (rho & 7)) * 8));
            }
        if (kt + 2 < NT) STGA(SLOT_A(cur, 0), 0, kt + 2);
        __builtin_amdgcn_s_barrier();
        asm volatile("s_waitcnt lgkmcnt(0)" ::: "memory");
        __builtin_amdgcn_s_setprio(1);
        #pragma unroll
        for (int mi = 0; mi < 4; ++mi) {
            acc[4 + mi][1] = MFMA16(aR[mi][0], bB1[0], acc[4 + mi][1]);
            acc[4 + mi][1] = MFMA16(aR[mi][1], bB1[1], acc[4 + mi][1]);
        }
        __builtin_amdgcn_s_setprio(0);
        __builtin_amdgcn_s_barrier();

        // ---- phase D: (mh1, nh0) ----
        if (kt + 2 < NT) STGB(SLOT_B(cur, 1), 1, kt + 2);
        __builtin_amdgcn_s_barrier();
        __builtin_amdgcn_s_setprio(1);
        #pragma unroll
        for (int mi = 0; mi < 4; ++mi) {
            acc[4 + mi][0] = MFMA16(aR[mi][0], bB0[0], acc[4 + mi][0]);
            acc[4 + mi][0] = MFMA16(aR[mi][1], bB0[1], acc[4 + mi][0]);
        }
        __builtin_amdgcn_s_setprio(0);
        __builtin_amdgcn_s_barrier();
    }
#undef STGA
#undef STGB
#undef SLOT_A
#undef SLOT_B

    const int region = n0 >> 10;  // 0=Q, 1=K, 2=V (128-tiles never straddle)
    if (region == 2) {
        #pragma unroll
        for (int nh = 0; nh < 2; ++nh) {
            const int d = n0 - 2048 + nh * 64 + wn * 16 + ln;
            const float bv = bkv[1024 + d];
            #pragma unroll
            for (int mh = 0; mh < 2; ++mh)
                #pragma unroll
                for (int mi = 0; mi < 4; ++mi) {
                    const int tok = m0 + mh * 128 + wm * 64 + mi * 16 + g * 4;
                    const int bb = tok >> 11, t4 = tok & 2047;
                    const f32x4 av = acc[mh * 4 + mi][nh];
                    ushort4 p4;
                    p4.x = f2bf(av[0] + bv); p4.y = f2bf(av[1] + bv);
                    p4.z = f2bf(av[2] + bv); p4.w = f2bf(av[3] + bv);
                    *(ushort4*)(Vtg + ((size_t)bb * 1024 + d) * 2048 + t4) = p4;
                }
        }
    } else {
        const int isQ = (region == 0);
        const float osc = isQ ? qscl : 1.f;
        #pragma unroll
        for (int nh = 0; nh < 2; ++nh) {
            const int col = n0 + nh * 64 + wn * 16 + ln;
            const float bv = isQ ? bq[col] : bkv[col - 1024];
            const int ck = isQ ? col : col - 1024;
            #pragma unroll
            for (int mh = 0; mh < 2; ++mh)
                #pragma unroll
                for (int mi = 0; mi < 4; ++mi) {
                    const int row = m0 + mh * 128 + wm * 64 + mi * 16 + g * 4;
                    const f32x4 av = acc[mh * 4 + mi][nh];
                    #pragma unroll
                    for (int r = 0; r < 4; ++r) {
                        const float vout = (av[r] + bv) * osc;
                        if (isQ)
                            Qb[(size_t)(row + r) * 1024 + ck] = f2bf(vout);
                        else
                            Kb[(size_t)(row + r) * 1024 + ck] = f2bf(vout);
                    }
                }
        }
    }
}

// ---------------------------------------------------------------------------
// Out-projection GEMM v3: 128x64 tile, BK=128 (8 iters, barriers halved vs
// BK=64). A/B stored as stacked 64-col subtiles so the proven per-64-col
// swizzle applies (c = kc*4+g in 0..15: ks = c>>3 selects subtile, c&7
// XORed with row&7). 512 blocks, T1 remap.
// ---------------------------------------------------------------------------
__global__ __launch_bounds__(256) void gemm_bt2(
    const unsigned short* __restrict__ A,    // Yb [4096][1024]
    const unsigned short* __restrict__ Bt,   // Wot [1024][1024]
    const float* __restrict__ bias,
    float* __restrict__ Cout)
{
    const int N = 1024, K = 1024;
    __shared__ __align__(16) unsigned short As[2 * 128 * 64];  // [ks][128][64]
    __shared__ __align__(16) unsigned short Bs[2 * 64 * 64];   // [ks][64][64]
    const int tid = threadIdx.x;
    const int w = tid >> 6, l = tid & 63, g = l >> 4, ln = l & 15;
    const int wm = w >> 1, wn = w & 1;
    const int dd = blockIdx.x;
    const int bid = (dd & 7) * 64 + (dd >> 3);   // T1 remap (512%8==0)
    const int m0 = (bid >> 4) * 128, n0 = (bid & 15) * 64;

    const int sr8 = w * 8 + (l >> 3);            // 0..31 (4 waves)
    const int sc  = (l & 7) ^ ((l >> 3) & 7);    // pre-swizzled source chunk
    const unsigned short* Asrc = A  + (size_t)m0 * K + sc * 8;
    const unsigned short* Bsrc = Bt + (size_t)n0 * K + sc * 8;

    f32x4 acc[4][2];
    #pragma unroll
    for (int i = 0; i < 4; ++i)
        #pragma unroll
        for (int j = 0; j < 2; ++j) acc[i][j] = (f32x4){0.f, 0.f, 0.f, 0.f};

    for (int k0 = 0; k0 < K; k0 += 128) {
        #pragma unroll
        for (int ks = 0; ks < 2; ++ks) {
            #pragma unroll
            for (int r_ = 0; r_ < 4; ++r_)
                __builtin_amdgcn_global_load_lds(
                    (const __attribute__((address_space(1))) void*)
                        (Asrc + (size_t)(r_ * 32 + sr8) * K + k0 + ks * 64),
                    (__attribute__((address_space(3))) void*)
                        (As + ks * 8192 + r_ * 2048 + w * 512 + l * 8),
                    16, 0, 0);
            #pragma unroll
            for (int r_ = 0; r_ < 2; ++r_)
                __builtin_amdgcn_global_load_lds(
                    (const __attribute__((address_space(1))) void*)
                        (Bsrc + (size_t)(r_ * 32 + sr8) * K + k0 + ks * 64),
                    (__attribute__((address_space(3))) void*)
                        (Bs + ks * 4096 + r_ * 2048 + w * 512 + l * 8),
                    16, 0, 0);
        }
        __syncthreads();
        bf16x8 af[4][4], bfr[2][4];
        #pragma unroll
        for (int mi = 0; mi < 4; ++mi)
            #pragma unroll
            for (int kc = 0; kc < 4; ++kc) {
                const int rho = wm * 64 + mi * 16 + ln, c = kc * 4 + g;
                af[mi][kc] = *(const bf16x8*)
                    (As + (c >> 3) * 8192 + rho * 64 + (((c & 7) ^ (rho & 7)) * 8));
            }
        #pragma unroll
        for (int ni = 0; ni < 2; ++ni)
            #pragma unroll
            for (int kc = 0; kc < 4; ++kc) {
                const int rho = wn * 32 + ni * 16 + ln, c = kc * 4 + g;
                bfr[ni][kc] = *(const bf16x8*)
                    (Bs + (c >> 3) * 4096 + rho * 64 + (((c & 7) ^ (rho & 7)) * 8));
            }
        __builtin_amdgcn_s_setprio(1);
        #pragma unroll
        for (int mi = 0; mi < 4; ++mi)
            #pragma unroll
            for (int ni = 0; ni < 2; ++ni)
                #pragma unroll
                for (int kc = 0; kc < 4; ++kc)
                    acc[mi][ni] = MFMA16(af[mi][kc], bfr[ni][kc], acc[mi][ni]);
        __builtin_amdgcn_s_setprio(0);
        __syncthreads();
    }

    #pragma unroll
    for (int n = 0; n < 2; ++n) {
        const int col = n0 + wn * 32 + n * 16 + ln;
        const float bv = bias[col];
        #pragma unroll
        for (int m = 0; m < 4; ++m) {
            const int row = m0 + wm * 64 + m * 16 + g * 4;
            #pragma unroll
            for (int r = 0; r < 4; ++r)
                Cout[(size_t)(row + r) * N + col] = acc[m][n][r] + bv;
        }
    }
}

// ---------------------------------------------------------------------------
// bf16 MFMA flash attention v9 (unchanged from R13, 63.8 us).
// ---------------------------------------------------------------------------
__global__ __launch_bounds__(256, 2) void attn_mfma(
    const unsigned short* __restrict__ Qb,
    const unsigned short* __restrict__ Kb,
    const unsigned short* __restrict__ Vtg,
    unsigned short* __restrict__ Yb)
{
    __shared__ __align__(16) unsigned short Ks[2][64 * 64];
    __shared__ __align__(16) unsigned short Vs[2][64 * 64];
    __shared__ __align__(16) unsigned short Pl[4][2][32 * 64];

    const int tid = threadIdx.x;
    const int w = tid >> 6, l = tid & 63, g = l >> 4, ln = l & 15;
    const int dd = blockIdx.x;
    const int bid = (dd & 7) * 64 + (dd >> 3);   // T1 XCD remap (512%8==0)
    const int qc = bid & 15, h = (bid >> 4) & 15, b = bid >> 8;
    const int qrow = b * L_ + qc * 128 + w * 32;

    const int sub = l >> 3;
    const int scc = (l & 7) ^ sub;               // pre-swizzled source chunk
    const unsigned short* ksrc = Kb  + (size_t)(b * L_) * 1024 + h * HD_ + scc * 8;
    const unsigned short* vsrc = Vtg + (size_t)(b * D_ + h * HD_) * 2048 + scc * 8;

#define STAGE(jj, bb) do {                                                    \
    _Pragma("unroll")                                                         \
    for (int i_ = 0; i_ < 2; ++i_) {                                          \
        const int rowK = w * 16 + i_ * 8 + sub;                               \
        __builtin_amdgcn_global_load_lds(                                     \
            (const __attribute__((address_space(1))) void*)                   \
                (ksrc + (size_t)((jj) * 64 + rowK) * 1024),                   \
            (__attribute__((address_space(3))) void*)                         \
                (&Ks[bb][w * 1024 + i_ * 512]), 16, 0, 0);                    \
        __builtin_amdgcn_global_load_lds(                                     \
            (const __attribute__((address_space(1))) void*)                   \
                (vsrc + (size_t)rowK * 2048 + (jj) * 64),                     \
            (__attribute__((address_space(3))) void*)                         \
                (&Vs[bb][w * 1024 + i_ * 512]), 16, 0, 0);                    \
    }                                                                         \
} while (0)

    bf16x8 qa[2][2];
    #pragma unroll
    for (int qt = 0; qt < 2; ++qt)
        #pragma unroll
        for (int c = 0; c < 2; ++c)
            qa[qt][c] = *(const bf16x8*)
                (Qb + (size_t)(qrow + qt * 16 + ln) * D_ + h * HD_ + c * 32 + g * 8);

    f32x4 o[2][4], lacc[2];
    #pragma unroll
    for (int qt = 0; qt < 2; ++qt) {
        #pragma unroll
        for (int dt = 0; dt < 4; ++dt) o[qt][dt] = (f32x4){0.f, 0.f, 0.f, 0.f};
        lacc[qt] = (f32x4){0.f, 0.f, 0.f, 0.f};
    }
    const short one_s = (short)0x3F80;  // bf16 1.0
    const bf16x8 ones = {one_s, one_s, one_s, one_s, one_s, one_s, one_s, one_s};

    unsigned short* Pw = &Pl[w][0][0];
    const int swzl = (ln & 7) << 3;     // K/V read XOR (16B granularity)
    const int swp  = (ln & 7) << 1;     // P chunk XOR (8B granularity)

    bf16x8 vbA[4][2], vbB[4][2];        // V frags carried across one body

#define S_CORE(BUF, PWS, VARR) do {                                           \
    const unsigned short* Kc = &Ks[BUF][0];                                   \
    const unsigned short* Vc = &Vs[BUF][0];                                   \
    bf16x8 kb[4][2];                                                          \
    _Pragma("unroll")                                                         \
    for (int kt = 0; kt < 4; ++kt)                                            \
        _Pragma("unroll")                                                     \
        for (int c = 0; c < 2; ++c)                                           \
            kb[kt][c] = *(const bf16x8*)                                      \
                (Kc + (kt * 16 + ln) * 64 + ((c * 32 + g * 8) ^ swzl));       \
    f32x4 s[2][4];                                                            \
    const f32x4 z = (f32x4){0.f, 0.f, 0.f, 0.f};                              \
    __builtin_amdgcn_s_setprio(1);                                            \
    _Pragma("unroll")                                                         \
    for (int qt = 0; qt < 2; ++qt)                                            \
        _Pragma("unroll")                                                     \
        for (int kt = 0; kt < 4; ++kt) {                                      \
            f32x4 t0 = MFMA16(kb[kt][0], qa[qt][0], z);                       \
            s[qt][kt] = MFMA16(kb[kt][1], qa[qt][1], t0);                     \
        }                                                                     \
    __builtin_amdgcn_s_setprio(0);                                            \
    _Pragma("unroll")                                                         \
    for (int dt = 0; dt < 4; ++dt)                                            \
        _Pragma("unroll")                                                     \
        for (int c2 = 0; c2 < 2; ++c2)                                        \
            VARR[dt][c2] = *(const bf16x8*)                                   \
                (Vc + (dt * 16 + ln) * 64 + ((c2 * 32 + g * 8) ^ swzl));      \
    _Pragma("unroll")                                                         \
    for (int qt = 0; qt < 2; ++qt) {                                          \
        const int prow = (qt * 16 + ln) * 64;                                 \
        _Pragma("unroll")                                                     \
        for (int kt = 0; kt < 4; ++kt) {                                      \
            union { float f; unsigned u; } c0, c1, c2u, c3;                   \
            c0.f = __builtin_exp2f(s[qt][kt][0]);                             \
            c1.f = __builtin_exp2f(s[qt][kt][1]);                             \
            c2u.f = __builtin_exp2f(s[qt][kt][2]);                            \
            c3.f = __builtin_exp2f(s[qt][kt][3]);                             \
            uint2 pk;                                                         \
            pk.x = __builtin_amdgcn_perm(c1.u, c0.u, 0x07060302u);            \
            pk.y = __builtin_amdgcn_perm(c3.u, c2u.u, 0x07060302u);           \
            *(uint2*)(Pw + (PWS) * 2048 + prow +                              \
                      (((kt * 4 + g) ^ swp) << 2)) = pk;                      \
        }                                                                     \
    }                                                                         \
} while (0)

#define O_PHASE(PPWS, PVARR) do {                                             \
    bf16x8 pa[2][2];                                                          \
    _Pragma("unroll")                                                         \
    for (int qt = 0; qt < 2; ++qt)                                            \
        _Pragma("unroll")                                                     \
        for (int c2 = 0; c2 < 2; ++c2)                                        \
            pa[qt][c2] = *(const bf16x8*)                                     \
                (Pw + (PPWS) * 2048 + (qt * 16 + ln) * 64 +                   \
                 (((c2 * 8 + g * 2) ^ swp) << 2));                            \
    __builtin_amdgcn_s_setprio(1);                                            \
    _Pragma("unroll")                                                         \
    for (int qt = 0; qt < 2; ++qt) {                                          \
        lacc[qt] = MFMA16(pa[qt][0], ones, lacc[qt]);                         \
        lacc[qt] = MFMA16(pa[qt][1], ones, lacc[qt]);                         \
        _Pragma("unroll")                                                     \
        for (int dt = 0; dt < 4; ++dt) {                                      \
            o[qt][dt] = MFMA16(pa[qt][0], PVARR[dt][0], o[qt][dt]);           \
            o[qt][dt] = MFMA16(pa[qt][1], PVARR[dt][1], o[qt][dt]);           \
        }                                                                     \
    }                                                                         \
    __builtin_amdgcn_s_setprio(0);                                            \
} while (0)

    STAGE(0, 0);
    __syncthreads();

    STAGE(1, 1);
    S_CORE(0, 0, vbA);
    __syncthreads();

    #pragma unroll 1
    for (int t = 1; t < 31; t += 2) {
        STAGE(t + 1, 0);
        O_PHASE(0, vbA);
        S_CORE(1, 1, vbB);
        __syncthreads();
        if (t + 2 < 32) STAGE(t + 2, 1);
        O_PHASE(1, vbB);
        S_CORE(0, 0, vbA);
        __syncthreads();
    }

    O_PHASE(0, vbA);
    S_CORE(1, 1, vbB);
    O_PHASE(1, vbB);
#undef O_PHASE
#undef S_CORE
#undef STAGE

    #pragma unroll
    for (int qt = 0; qt < 2; ++qt)
        #pragma unroll
        for (int r = 0; r < 4; ++r) {
            const float inv = 1.f / lacc[qt][r];
            const int row = qrow + qt * 16 + g * 4 + r;
            #pragma unroll
            for (int dt = 0; dt < 4; ++dt)
                Yb[(size_t)row * D_ + h * HD_ + dt * 16 + ln] =
                    f2bf(o[qt][dt][r] * inv);
        }
}

// ---------------------------------------------------------------------------
extern "C" void kernel_launch(void* const* d_in, const int* in_sizes, int n_in,
                              void* d_out, int out_size, void* d_ws, size_t ws_size,
                              hipStream_t stream)
{
    const float* x   = (const float*)d_in[0];
    const float* Wq  = (const float*)d_in[1];
    const float* bq  = (const float*)d_in[2];
    const float* Wkv = (const float*)d_in[3];
    const float* bkv = (const float*)d_in[4];
    const float* Wo  = (const float*)d_in[5];
    const float* bo  = (const float*)d_in[6];
    float* out = (float*)d_out;

    const int M = B_ * L_;  // 4096
    unsigned short* ws = (unsigned short*)d_ws;
    unsigned short* xb   = ws;                          // 8MB
    unsigned short* Wqt  = xb   + (size_t)M * D_;       // 2MB \ adjacent =
    unsigned short* Wkvt = Wqt  + (size_t)D_ * D_;      // 4MB / Bt[3072][1024]
    unsigned short* Wot  = Wkvt + (size_t)2 * D_ * D_;  // 2MB
    unsigned short* Qb   = Wot  + (size_t)D_ * D_;      // 8MB
    unsigned short* Kb   = Qb   + (size_t)M * D_;       // 8MB
    unsigned short* Vtg  = Kb   + (size_t)M * D_;       // 8MB
    unsigned short* Yb   = Vtg  + (size_t)B_ * D_ * L_; // 8MB

    const float QSCL = 0.125f * 1.44269504089f;  // 1/sqrt(HD) * log2(e)

    // prep: x -> bf16 + all weight transposes, one launch
    prep_all<<<dim3(32, 32, 5), 256, 0, stream>>>(
        x, Wq, Wkv, Wo, xb, Wqt, Wkvt, Wot);

    // fused QKV projection, 256x128 8-phase (384 blocks)
    gemm_qkv8<<<dim3(384), 512, 0, stream>>>(xb, Wqt, bq, bkv, Qb, Kb, Vtg, QSCL);

    // flash attention -> Yb bf16 [M][D]
    attn_mfma<<<dim3(B_ * H_ * (L_ / 128)), 256, 0, stream>>>(Qb, Kb, Vtg, Yb);

    // out = Yb@Wo + bo (fp32 out), 128x64 tiles, BK=128, 512 blocks
    gemm_bt2<<<dim3(512), 256, 0, stream>>>(Yb, Wot, bo, out);
}

// Round 15
// 119.593 us; speedup vs baseline: 1.0659x; 1.0659x over previous
//
#include <hip/hip_runtime.h>

#define B_  2
#define L_  2048
#define D_  1024
#define H_  16
#define HD_ 64

typedef __attribute__((ext_vector_type(8))) short bf16x8;
typedef __attribute__((ext_vector_type(4))) float f32x4;

#define MFMA16(a, b, c) __builtin_amdgcn_mfma_f32_16x16x32_bf16(a, b, c, 0, 0, 0)

__device__ __forceinline__ unsigned short f2bf(float f) {
    union { float f; unsigned u; } v; v.f = f;
    unsigned r = v.u + 0x7FFFu + ((v.u >> 16) & 1u);
    return (unsigned short)(r >> 16);
}

// ---------------------------------------------------------------------------
// Merged prep: z<4 -> weight transposes (fp32 [K][N] -> bf16 [N][K]);
// z==4 -> x fp32 -> bf16.
// ---------------------------------------------------------------------------
__global__ __launch_bounds__(256) void prep_all(
    const float* __restrict__ x,
    const float* __restrict__ Wq, const float* __restrict__ Wkv,
    const float* __restrict__ Wo,
    unsigned short* __restrict__ xb,
    unsigned short* __restrict__ Wqt, unsigned short* __restrict__ Wkvt,
    unsigned short* __restrict__ Wot)
{
    const int z = blockIdx.z;
    if (z == 4) {
        const int bidl = blockIdx.y * 32 + blockIdx.x;   // 0..1023
        const int n4 = B_ * L_ * D_ / 4;
        for (int i = bidl * 256 + threadIdx.x; i < n4; i += 1024 * 256) {
            float4 v = *(const float4*)(x + (size_t)i * 4);
            ushort4 u;
            u.x = f2bf(v.x); u.y = f2bf(v.y); u.z = f2bf(v.z); u.w = f2bf(v.w);
            *(ushort4*)(xb + (size_t)i * 4) = u;
        }
        return;
    }
    __shared__ float t[32][33];
    const float* W;  unsigned short* Wt;  int N, nc;
    if (z == 0)      { W = Wq;  Wt = Wqt;  N = 1024; nc = 0; }
    else if (z == 1) { W = Wo;  Wt = Wot;  N = 1024; nc = 0; }
    else             { W = Wkv; Wt = Wkvt; N = 2048; nc = (z - 2) * 1024; }
    const int tx = threadIdx.x & 31, ty = threadIdx.x >> 5;
    const int n0 = nc + blockIdx.x * 32, k0 = blockIdx.y * 32;
    #pragma unroll
    for (int r = 0; r < 4; ++r)
        t[ty + r * 8][tx] = W[(size_t)(k0 + ty + r * 8) * N + n0 + tx];
    __syncthreads();
    #pragma unroll
    for (int r = 0; r < 4; ++r)
        Wt[(size_t)(n0 + ty + r * 8) * 1024 + k0 + tx] = f2bf(t[tx][ty + r * 8]);
}

// ---------------------------------------------------------------------------
// Fused QKV projection v3: 128x384 tile -> grid 32x8 = 256 blocks = EXACTLY
// full fill (one scheduling round, makespan 0.75x of the 192-block 256^2).
// 8-phase schedule (T2+T3+T4+T5), mirror of the proven R13 loop.
// 8 waves = 2wm x 4wn; per wave M = 2mh x (wm*32 + 2mi x 16),
// N = 2nh x (wn*48 + 3ni x 16); per phase 12 MFMA.
// LDS 128KB: A = 2dbuf x 2half x [64][64], B = 2dbuf x 2half x [192][64].
// Stages: phA A-h1(kt+1)[1], phB B-h0(kt+1)[3], phC A-h0(kt+2)[1],
// phD B-h1(kt+2)[3]; loop-top vmcnt(4) keeps phC+phD's 4 loads in flight.
// RACE FIX vs R13: stage unconditionally with clamped kt (dead-slot writes
// on the last iterations) so vmcnt accounting is uniform -- the guarded
// version left the final iteration's phase-A operand possibly in flight.
// Epilogue routes per 16-col fragment (tiles straddle Q/K/V regions).
// ---------------------------------------------------------------------------
__global__ __launch_bounds__(512, 1) void gemm_qkv8(
    const unsigned short* __restrict__ A,    // xb [4096][1024]
    const unsigned short* __restrict__ Bt,   // Wqkvt [3072][1024]
    const float* __restrict__ bq, const float* __restrict__ bkv,
    unsigned short* __restrict__ Qb, unsigned short* __restrict__ Kb,
    unsigned short* __restrict__ Vtg, float qscl)
{
    const int KDIM = 1024, NT = 16;  // K-tiles of 64
    __shared__ __align__(16) unsigned short lds[65536];  // 128 KiB

    const int tid = threadIdx.x;
    const int w = tid >> 6, l = tid & 63, g = l >> 4, ln = l & 15;
    const int wm = (w >> 2) & 1, wn = w & 3;

    // T1 XCD remap: 256 blocks -> 32 contiguous per XCD
    const int lin = blockIdx.x;
    const int wg = (lin & 7) * 32 + (lin >> 3);
    const int by = wg >> 3, bx = wg & 7;     // 32 x 8
    const int m0 = by * 128, n0 = bx * 384;

    const int sr8 = w * 8 + (l >> 3);        // 0..63
    const int sc  = (l & 7) ^ ((l >> 3) & 7);
    const unsigned short* Asrc = A  + (size_t)m0 * KDIM + sc * 8;
    const unsigned short* Bsrc = Bt + (size_t)n0 * KDIM + sc * 8;

#define SLOT_A(d, h) (lds + ((d) * 2 + (h)) * 4096)            // [64][64] u16
#define SLOT_B(d, h) (lds + 16384 + ((d) * 2 + (h)) * 12288)   // [192][64] u16

    // A half-tile: 64 rows -> 1 load/thread
#define STGA(slotp, hh, kt_) do {                                             \
    const int rowA_ = (hh) * 64 + sr8;                                        \
    __builtin_amdgcn_global_load_lds(                                         \
        (const __attribute__((address_space(1))) void*)                       \
            (Asrc + (size_t)rowA_ * KDIM + (kt_) * 64),                       \
        (__attribute__((address_space(3))) void*)((slotp) + tid * 8),         \
        16, 0, 0);                                                            \
} while (0)

    // B half-tile: 192 rows -> 3 loads/thread
#define STGB(slotp, hh, kt_) do {                                             \
    _Pragma("unroll")                                                         \
    for (int r_ = 0; r_ < 3; ++r_) {                                          \
        const int rowB_ = (hh) * 192 + r_ * 64 + sr8;                         \
        __builtin_amdgcn_global_load_lds(                                     \
            (const __attribute__((address_space(1))) void*)                   \
                (Bsrc + (size_t)rowB_ * KDIM + (kt_) * 64),                   \
            (__attribute__((address_space(3))) void*)                         \
                ((slotp) + r_ * 4096 + tid * 8),                              \
            16, 0, 0);                                                        \
    }                                                                         \
} while (0)

    f32x4 acc[4][6];   // [mh*2+mi][nh*3+ni]
    #pragma unroll
    for (int i = 0; i < 4; ++i)
        #pragma unroll
        for (int j = 0; j < 6; ++j) acc[i][j] = (f32x4){0.f, 0.f, 0.f, 0.f};

    bf16x8 aR[2][2], bB0[3][2], bB1[3][2];

    // prologue (age order); last 2 macros = 4 loads stay in flight
    STGA(SLOT_A(0, 0), 0, 0);
    STGB(SLOT_B(0, 1), 1, 0);
    STGA(SLOT_A(0, 1), 1, 0);
    STGB(SLOT_B(0, 0), 0, 0);
    STGA(SLOT_A(1, 0), 0, 1);
    STGB(SLOT_B(1, 1), 1, 1);

    #pragma unroll 1
    for (int kt = 0; kt < NT; ++kt) {
        const int cur = kt & 1, nxt = cur ^ 1;
        const int kt1 = (kt + 1 < NT) ? kt + 1 : NT - 1;   // clamped (race fix)
        const int kt2 = (kt + 2 < NT) ? kt + 2 : NT - 1;
        asm volatile("s_waitcnt vmcnt(4)" ::: "memory");
        __builtin_amdgcn_s_barrier();

        // ---- phase A: (mh0, nh0) ----
        #pragma unroll
        for (int mi = 0; mi < 2; ++mi)
            #pragma unroll
            for (int kc = 0; kc < 2; ++kc) {
                const int rho = wm * 32 + mi * 16 + ln, c = kc * 4 + g;
                aR[mi][kc] = *(const bf16x8*)
                    (SLOT_A(cur, 0) + rho * 64 + ((c ^ (rho & 7)) * 8));
            }
        #pragma unroll
        for (int ni = 0; ni < 3; ++ni)
            #pragma unroll
            for (int kc = 0; kc < 2; ++kc) {
                const int rho = wn * 48 + ni * 16 + ln, c = kc * 4 + g;
                bB0[ni][kc] = *(const bf16x8*)
                    (SLOT_B(cur, 0) + rho * 64 + ((c ^ (rho & 7)) * 8));
            }
        STGA(SLOT_A(nxt, 1), 1, kt1);
        __builtin_amdgcn_s_barrier();
        asm volatile("s_waitcnt lgkmcnt(0)" ::: "memory");
        __builtin_amdgcn_s_setprio(1);
        #pragma unroll
        for (int mi = 0; mi < 2; ++mi)
            #pragma unroll
            for (int ni = 0; ni < 3; ++ni) {
                acc[mi][ni] = MFMA16(aR[mi][0], bB0[ni][0], acc[mi][ni]);
                acc[mi][ni] = MFMA16(aR[mi][1], bB0[ni][1], acc[mi][ni]);
            }
        __builtin_amdgcn_s_setprio(0);
        __builtin_amdgcn_s_barrier();

        // ---- phase B: (mh0, nh1) ----
        #pragma unroll
        for (int ni = 0; ni < 3; ++ni)
            #pragma unroll
            for (int kc = 0; kc < 2; ++kc) {
                const int rho = wn * 48 + ni * 16 + ln, c = kc * 4 + g;
                bB1[ni][kc] = *(const bf16x8*)
                    (SLOT_B(cur, 1) + rho * 64 + ((c ^ (rho & 7)) * 8));
            }
        STGB(SLOT_B(nxt, 0), 0, kt1);
        __builtin_amdgcn_s_barrier();
        asm volatile("s_waitcnt lgkmcnt(0)" ::: "memory");
        __builtin_amdgcn_s_setprio(1);
        #pragma unroll
        for (int mi = 0; mi < 2; ++mi)
            #pragma unroll
            for (int ni = 0; ni < 3; ++ni) {
                acc[mi][3 + ni] = MFMA16(aR[mi][0], bB1[ni][0], acc[mi][3 + ni]);
                acc[mi][3 + ni] = MFMA16(aR[mi][1], bB1[ni][1], acc[mi][3 + ni]);
            }
        __builtin_amdgcn_s_setprio(0);
        __builtin_amdgcn_s_barrier();

        // ---- phase C: (mh1, nh1) ----
        #pragma unroll
        for (int mi = 0; mi < 2; ++mi)
            #pragma unroll
            for (int kc = 0; kc < 2; ++kc) {
                const int rho = wm * 32 + mi * 16 + ln, c = kc * 4 + g;
                aR[mi][kc] = *(const bf16x8*)
                    (SLOT_A(cur, 1) + rho * 64 + ((c ^ (rho & 7)) * 8));
            }
        STGA(SLOT_A(cur, 0), 0, kt2);
        __builtin_amdgcn_s_barrier();
        asm volatile("s_waitcnt lgkmcnt(0)" ::: "memory");
        __builtin_amdgcn_s_setprio(1);
        #pragma unroll
        for (int mi = 0; mi < 2; ++mi)
            #pragma unroll
            for (int ni = 0; ni < 3; ++ni) {
                acc[2 + mi][3 + ni] = MFMA16(aR[mi][0], bB1[ni][0], acc[2 + mi][3 + ni]);
                acc[2 + mi][3 + ni] = MFMA16(aR[mi][1], bB1[ni][1], acc[2 + mi][3 + ni]);
            }
        __builtin_amdgcn_s_setprio(0);
        __builtin_amdgcn_s_barrier();

        // ---- phase D: (mh1, nh0) ----
        STGB(SLOT_B(cur, 1), 1, kt2);
        __builtin_amdgcn_s_barrier();
        __builtin_amdgcn_s_setprio(1);
        #pragma unroll
        for (int mi = 0; mi < 2; ++mi)
            #pragma unroll
            for (int ni = 0; ni < 3; ++ni) {
                acc[2 + mi][ni] = MFMA16(aR[mi][0], bB0[ni][0], acc[2 + mi][ni]);
                acc[2 + mi][ni] = MFMA16(aR[mi][1], bB0[ni][1], acc[2 + mi][ni]);
            }
        __builtin_amdgcn_s_setprio(0);
        __builtin_amdgcn_s_barrier();
    }
#undef STGA
#undef STGB
#undef SLOT_A
#undef SLOT_B

    // epilogue: route per 16-col fragment (region = col>>10; no straddle)
    #pragma unroll
    for (int nh = 0; nh < 2; ++nh)
        #pragma unroll
        for (int ni = 0; ni < 3; ++ni) {
            const int col = n0 + nh * 192 + wn * 48 + ni * 16 + ln;
            const int region = col >> 10;
            if (region == 2) {
                const int d = col - 2048;
                const float bv = bkv[1024 + d];
                #pragma unroll
                for (int mh = 0; mh < 2; ++mh)
                    #pragma unroll
                    for (int mi = 0; mi < 2; ++mi) {
                        const int tok = m0 + mh * 64 + wm * 32 + mi * 16 + g * 4;
                        const int bb = tok >> 11, t4 = tok & 2047;
                        const f32x4 av = acc[mh * 2 + mi][nh * 3 + ni];
                        ushort4 p4;
                        p4.x = f2bf(av[0] + bv); p4.y = f2bf(av[1] + bv);
                        p4.z = f2bf(av[2] + bv); p4.w = f2bf(av[3] + bv);
                        *(ushort4*)(Vtg + ((size_t)bb * 1024 + d) * 2048 + t4) = p4;
                    }
            } else {
                const int isQ = (region == 0);
                const float osc = isQ ? qscl : 1.f;
                const float bv = isQ ? bq[col] : bkv[col - 1024];
                const int ck = isQ ? col : col - 1024;
                #pragma unroll
                for (int mh = 0; mh < 2; ++mh)
                    #pragma unroll
                    for (int mi = 0; mi < 2; ++mi) {
                        const int row = m0 + mh * 64 + wm * 32 + mi * 16 + g * 4;
                        const f32x4 av = acc[mh * 2 + mi][nh * 3 + ni];
                        #pragma unroll
                        for (int r = 0; r < 4; ++r) {
                            const float vout = (av[r] + bv) * osc;
                            if (isQ)
                                Qb[(size_t)(row + r) * 1024 + ck] = f2bf(vout);
                            else
                                Kb[(size_t)(row + r) * 1024 + ck] = f2bf(vout);
                        }
                    }
            }
        }
}

// ---------------------------------------------------------------------------
// Out-projection GEMM v2 (R13 verbatim): 128x64 tile, BK=64, swizzled,
// 512 blocks, T1 remap.
// ---------------------------------------------------------------------------
__global__ __launch_bounds__(256) void gemm_bt2(
    const unsigned short* __restrict__ A,    // Yb [4096][1024]
    const unsigned short* __restrict__ Bt,   // Wot [1024][1024]
    const float* __restrict__ bias,
    float* __restrict__ Cout)
{
    const int N = 1024, K = 1024;
    __shared__ __align__(16) unsigned short As[128 * 64];
    __shared__ __align__(16) unsigned short Bs[64 * 64];
    const int tid = threadIdx.x;
    const int w = tid >> 6, l = tid & 63, g = l >> 4, ln = l & 15;
    const int wm = w >> 1, wn = w & 1;
    const int dd = blockIdx.x;
    const int bid = (dd & 7) * 64 + (dd >> 3);   // T1 remap (512%8==0)
    const int m0 = (bid >> 4) * 128, n0 = (bid & 15) * 64;

    const int sr8 = w * 8 + (l >> 3);            // 0..31
    const int sc  = (l & 7) ^ ((l >> 3) & 7);    // pre-swizzled source chunk
    const unsigned short* Asrc = A  + (size_t)m0 * K + sc * 8;
    const unsigned short* Bsrc = Bt + (size_t)n0 * K + sc * 8;

    f32x4 acc[4][2];
    #pragma unroll
    for (int i = 0; i < 4; ++i)
        #pragma unroll
        for (int j = 0; j < 2; ++j) acc[i][j] = (f32x4){0.f, 0.f, 0.f, 0.f};

    for (int k0 = 0; k0 < K; k0 += 64) {
        #pragma unroll
        for (int r_ = 0; r_ < 4; ++r_)
            __builtin_amdgcn_global_load_lds(
                (const __attribute__((address_space(1))) void*)
                    (Asrc + (size_t)(r_ * 32 + sr8) * K + k0),
                (__attribute__((address_space(3))) void*)
                    (As + r_ * 2048 + w * 512 + l * 8),
                16, 0, 0);
        #pragma unroll
        for (int r_ = 0; r_ < 2; ++r_)
            __builtin_amdgcn_global_load_lds(
                (const __attribute__((address_space(1))) void*)
                    (Bsrc + (size_t)(r_ * 32 + sr8) * K + k0),
                (__attribute__((address_space(3))) void*)
                    (Bs + r_ * 2048 + w * 512 + l * 8),
                16, 0, 0);
        __syncthreads();
        bf16x8 af[4][2], bfr[2][2];
        #pragma unroll
        for (int mi = 0; mi < 4; ++mi)
            #pragma unroll
            for (int kc = 0; kc < 2; ++kc) {
                const int rho = wm * 64 + mi * 16 + ln, c = kc * 4 + g;
                af[mi][kc] = *(const bf16x8*)
                    (As + rho * 64 + ((c ^ (rho & 7)) * 8));
            }
        #pragma unroll
        for (int ni = 0; ni < 2; ++ni)
            #pragma unroll
            for (int kc = 0; kc < 2; ++kc) {
                const int rho = wn * 32 + ni * 16 + ln, c = kc * 4 + g;
                bfr[ni][kc] = *(const bf16x8*)
                    (Bs + rho * 64 + ((c ^ (rho & 7)) * 8));
            }
        __builtin_amdgcn_s_setprio(1);
        #pragma unroll
        for (int mi = 0; mi < 4; ++mi)
            #pragma unroll
            for (int ni = 0; ni < 2; ++ni) {
                acc[mi][ni] = MFMA16(af[mi][0], bfr[ni][0], acc[mi][ni]);
                acc[mi][ni] = MFMA16(af[mi][1], bfr[ni][1], acc[mi][ni]);
            }
        __builtin_amdgcn_s_setprio(0);
        __syncthreads();
    }

    #pragma unroll
    for (int n = 0; n < 2; ++n) {
        const int col = n0 + wn * 32 + n * 16 + ln;
        const float bv = bias[col];
        #pragma unroll
        for (int m = 0; m < 4; ++m) {
            const int row = m0 + wm * 64 + m * 16 + g * 4;
            #pragma unroll
            for (int r = 0; r < 4; ++r)
                Cout[(size_t)(row + r) * N + col] = acc[m][n][r] + bv;
        }
    }
}

// ---------------------------------------------------------------------------
// bf16 MFMA flash attention v9 (R13 verbatim, 62.9-63.8 us).
// ---------------------------------------------------------------------------
__global__ __launch_bounds__(256, 2) void attn_mfma(
    const unsigned short* __restrict__ Qb,
    const unsigned short* __restrict__ Kb,
    const unsigned short* __restrict__ Vtg,
    unsigned short* __restrict__ Yb)
{
    __shared__ __align__(16) unsigned short Ks[2][64 * 64];
    __shared__ __align__(16) unsigned short Vs[2][64 * 64];
    __shared__ __align__(16) unsigned short Pl[4][2][32 * 64];

    const int tid = threadIdx.x;
    const int w = tid >> 6, l = tid & 63, g = l >> 4, ln = l & 15;
    const int dd = blockIdx.x;
    const int bid = (dd & 7) * 64 + (dd >> 3);   // T1 XCD remap (512%8==0)
    const int qc = bid & 15, h = (bid >> 4) & 15, b = bid >> 8;
    const int qrow = b * L_ + qc * 128 + w * 32;

    const int sub = l >> 3;
    const int scc = (l & 7) ^ sub;               // pre-swizzled source chunk
    const unsigned short* ksrc = Kb  + (size_t)(b * L_) * 1024 + h * HD_ + scc * 8;
    const unsigned short* vsrc = Vtg + (size_t)(b * D_ + h * HD_) * 2048 + scc * 8;

#define STAGE(jj, bb) do {                                                    \
    _Pragma("unroll")                                                         \
    for (int i_ = 0; i_ < 2; ++i_) {                                          \
        const int rowK = w * 16 + i_ * 8 + sub;                               \
        __builtin_amdgcn_global_load_lds(                                     \
            (const __attribute__((address_space(1))) void*)                   \
                (ksrc + (size_t)((jj) * 64 + rowK) * 1024),                   \
            (__attribute__((address_space(3))) void*)                         \
                (&Ks[bb][w * 1024 + i_ * 512]), 16, 0, 0);                    \
        __builtin_amdgcn_global_load_lds(                                     \
            (const __attribute__((address_space(1))) void*)                   \
                (vsrc + (size_t)rowK * 2048 + (jj) * 64),                     \
            (__attribute__((address_space(3))) void*)                         \
                (&Vs[bb][w * 1024 + i_ * 512]), 16, 0, 0);                    \
    }                                                                         \
} while (0)

    bf16x8 qa[2][2];
    #pragma unroll
    for (int qt = 0; qt < 2; ++qt)
        #pragma unroll
        for (int c = 0; c < 2; ++c)
            qa[qt][c] = *(const bf16x8*)
                (Qb + (size_t)(qrow + qt * 16 + ln) * D_ + h * HD_ + c * 32 + g * 8);

    f32x4 o[2][4], lacc[2];
    #pragma unroll
    for (int qt = 0; qt < 2; ++qt) {
        #pragma unroll
        for (int dt = 0; dt < 4; ++dt) o[qt][dt] = (f32x4){0.f, 0.f, 0.f, 0.f};
        lacc[qt] = (f32x4){0.f, 0.f, 0.f, 0.f};
    }
    const short one_s = (short)0x3F80;  // bf16 1.0
    const bf16x8 ones = {one_s, one_s, one_s, one_s, one_s, one_s, one_s, one_s};

    unsigned short* Pw = &Pl[w][0][0];
    const int swzl = (ln & 7) << 3;     // K/V read XOR (16B granularity)
    const int swp  = (ln & 7) << 1;     // P chunk XOR (8B granularity)

    bf16x8 vbA[4][2], vbB[4][2];        // V frags carried across one body

#define S_CORE(BUF, PWS, VARR) do {                                           \
    const unsigned short* Kc = &Ks[BUF][0];                                   \
    const unsigned short* Vc = &Vs[BUF][0];                                   \
    bf16x8 kb[4][2];                                                          \
    _Pragma("unroll")                                                         \
    for (int kt = 0; kt < 4; ++kt)                                            \
        _Pragma("unroll")                                                     \
        for (int c = 0; c < 2; ++c)                                           \
            kb[kt][c] = *(const bf16x8*)                                      \
                (Kc + (kt * 16 + ln) * 64 + ((c * 32 + g * 8) ^ swzl));       \
    f32x4 s[2][4];                                                            \
    const f32x4 z = (f32x4){0.f, 0.f, 0.f, 0.f};                              \
    __builtin_amdgcn_s_setprio(1);                                            \
    _Pragma("unroll")                                                         \
    for (int qt = 0; qt < 2; ++qt)                                            \
        _Pragma("unroll")                                                     \
        for (int kt = 0; kt < 4; ++kt) {                                      \
            f32x4 t0 = MFMA16(kb[kt][0], qa[qt][0], z);                       \
            s[qt][kt] = MFMA16(kb[kt][1], qa[qt][1], t0);                     \
        }                                                                     \
    __builtin_amdgcn_s_setprio(0);                                            \
    _Pragma("unroll")                                                         \
    for (int dt = 0; dt < 4; ++dt)                                            \
        _Pragma("unroll")                                                     \
        for (int c2 = 0; c2 < 2; ++c2)                                        \
            VARR[dt][c2] = *(const bf16x8*)                                   \
                (Vc + (dt * 16 + ln) * 64 + ((c2 * 32 + g * 8) ^ swzl));      \
    _Pragma("unroll")                                                         \
    for (int qt = 0; qt < 2; ++qt) {                                          \
        const int prow = (qt * 16 + ln) * 64;                                 \
        _Pragma("unroll")                                                     \
        for (int kt = 0; kt < 4; ++kt) {                                      \
            union { float f; unsigned u; } c0, c1, c2u, c3;                   \
            c0.f = __builtin_exp2f(s[qt][kt][0]);                             \
            c1.f = __builtin_exp2f(s[qt][kt][1]);                             \
            c2u.f = __builtin_exp2f(s[qt][kt][2]);                            \
            c3.f = __builtin_exp2f(s[qt][kt][3]);                             \
            uint2 pk;                                                         \
            pk.x = __builtin_amdgcn_perm(c1.u, c0.u, 0x07060302u);            \
            pk.y = __builtin_amdgcn_perm(c3.u, c2u.u, 0x07060302u);           \
            *(uint2*)(Pw + (PWS) * 2048 + prow +                              \
                      (((kt * 4 + g) ^ swp) << 2)) = pk;                      \
        }                                                                     \
    }                                                                         \
} while (0)

#define O_PHASE(PPWS, PVARR) do {                                             \
    bf16x8 pa[2][2];                                                          \
    _Pragma("unroll")                                                         \
    for (int qt = 0; qt < 2; ++qt)                                            \
        _Pragma("unroll")                                                     \
        for (int c2 = 0; c2 < 2; ++c2)                                        \
            pa[qt][c2] = *(const bf16x8*)                                     \
                (Pw + (PPWS) * 2048 + (qt * 16 + ln) * 64 +                   \
                 (((c2 * 8 + g * 2) ^ swp) << 2));                            \
    __builtin_amdgcn_s_setprio(1);                                            \
    _Pragma("unroll")                                                         \
    for (int qt = 0; qt < 2; ++qt) {                                          \
        lacc[qt] = MFMA16(pa[qt][0], ones, lacc[qt]);                         \
        lacc[qt] = MFMA16(pa[qt][1], ones, lacc[qt]);                         \
        _Pragma("unroll")                                                     \
        for (int dt = 0; dt < 4; ++dt) {                                      \
            o[qt][dt] = MFMA16(pa[qt][0], PVARR[dt][0], o[qt][dt]);           \
            o[qt][dt] = MFMA16(pa[qt][1], PVARR[dt][1], o[qt][dt]);           \
        }                                                                     \
    }                                                                         \
    __builtin_amdgcn_s_setprio(0);                                            \
} while (0)

    STAGE(0, 0);
    __syncthreads();

    STAGE(1, 1);
    S_CORE(0, 0, vbA);
    __syncthreads();

    #pragma unroll 1
    for (int t = 1; t < 31; t += 2) {
        STAGE(t + 1, 0);
        O_PHASE(0, vbA);
        S_CORE(1, 1, vbB);
        __syncthreads();
        if (t + 2 < 32) STAGE(t + 2, 1);
        O_PHASE(1, vbB);
        S_CORE(0, 0, vbA);
        __syncthreads();
    }

    O_PHASE(0, vbA);
    S_CORE(1, 1, vbB);
    O_PHASE(1, vbB);
#undef O_PHASE
#undef S_CORE
#undef STAGE

    #pragma unroll
    for (int qt = 0; qt < 2; ++qt)
        #pragma unroll
        for (int r = 0; r < 4; ++r) {
            const float inv = 1.f / lacc[qt][r];
            const int row = qrow + qt * 16 + g * 4 + r;
            #pragma unroll
            for (int dt = 0; dt < 4; ++dt)
                Yb[(size_t)row * D_ + h * HD_ + dt * 16 + ln] =
                    f2bf(o[qt][dt][r] * inv);
        }
}

// ---------------------------------------------------------------------------
extern "C" void kernel_launch(void* const* d_in, const int* in_sizes, int n_in,
                              void* d_out, int out_size, void* d_ws, size_t ws_size,
                              hipStream_t stream)
{
    const float* x   = (const float*)d_in[0];
    const float* Wq  = (const float*)d_in[1];
    const float* bq  = (const float*)d_in[2];
    const float* Wkv = (const float*)d_in[3];
    const float* bkv = (const float*)d_in[4];
    const float* Wo  = (const float*)d_in[5];
    const float* bo  = (const float*)d_in[6];
    float* out = (float*)d_out;

    const int M = B_ * L_;  // 4096
    unsigned short* ws = (unsigned short*)d_ws;
    unsigned short* xb   = ws;                          // 8MB
    unsigned short* Wqt  = xb   + (size_t)M * D_;       // 2MB \ adjacent =
    unsigned short* Wkvt = Wqt  + (size_t)D_ * D_;      // 4MB / Bt[3072][1024]
    unsigned short* Wot  = Wkvt + (size_t)2 * D_ * D_;  // 2MB
    unsigned short* Qb   = Wot  + (size_t)D_ * D_;      // 8MB
    unsigned short* Kb   = Qb   + (size_t)M * D_;       // 8MB
    unsigned short* Vtg  = Kb   + (size_t)M * D_;       // 8MB
    unsigned short* Yb   = Vtg  + (size_t)B_ * D_ * L_; // 8MB

    const float QSCL = 0.125f * 1.44269504089f;  // 1/sqrt(HD) * log2(e)

    // prep: x -> bf16 + all weight transposes, one launch
    prep_all<<<dim3(32, 32, 5), 256, 0, stream>>>(
        x, Wq, Wkv, Wo, xb, Wqt, Wkvt, Wot);

    // fused QKV projection, 128x384 8-phase (256 blocks = full fill)
    gemm_qkv8<<<dim3(256), 512, 0, stream>>>(xb, Wqt, bq, bkv, Qb, Kb, Vtg, QSCL);

    // flash attention -> Yb bf16 [M][D]
    attn_mfma<<<dim3(B_ * H_ * (L_ / 128)), 256, 0, stream>>>(Qb, Kb, Vtg, Yb);

    // out = Yb@Wo + bo (fp32 out), 128x64 tiles, BK=64, 512 blocks
    gemm_bt2<<<dim3(512), 256, 0, stream>>>(Yb, Wot, bo, out);
}